// Round 3
// baseline (360.471 us; speedup 1.0000x reference)
//
#include <hip/hip_runtime.h>

// Talking-heads MHSA, MI355X (gfx950).
// k1: QKV projection (f32 GEMM, outputs bf16; V stored transposed [b][h][d][p])
// k2: fused flash attention, all 8 heads per block, bf16 MFMA 16x16x32,
//     talking-heads mix + bias + online softmax in f32. KV split in 2 -> partials.
// k3: split-combine + output projection.

typedef __attribute__((ext_vector_type(8))) short short8v;  // 8 x bf16
typedef __attribute__((ext_vector_type(4))) float f32x4;

static __device__ __forceinline__ unsigned short f2bf(float f) {
  union { float f; unsigned u; } v; v.f = f;
  return (unsigned short)((v.u + 0x7FFFu + ((v.u >> 16) & 1u)) >> 16);
}

static __device__ __forceinline__ void load_lds_128(const void* g, void* lp) {
  // dest = wave-uniform LDS base + lane*16 (HW); src is per-lane global addr
  __builtin_amdgcn_global_load_lds(
      (const __attribute__((address_space(1))) void*)g,
      (__attribute__((address_space(3))) void*)lp, 16, 0, 0);
}

// ---------------- kernel 1: QKV projection ----------------
__global__ __launch_bounds__(256) void qkv_kernel(
    const float* __restrict__ x, const float* __restrict__ Wqkv,
    unsigned short* __restrict__ q_ws, unsigned short* __restrict__ k_ws,
    unsigned short* __restrict__ v_t) {
  __shared__ float xl[8][128];
  const int tid = threadIdx.x;
  const int rowbase = blockIdx.x * 8;
  {
    int r = tid >> 5, k4 = (tid & 31) * 4;
    *(float4*)&xl[r][k4] = *(const float4*)&x[(size_t)(rowbase + r) * 128 + k4];
  }
  __syncthreads();
  float acc[8][3];
#pragma unroll
  for (int r = 0; r < 8; ++r) { acc[r][0] = 0.f; acc[r][1] = 0.f; acc[r][2] = 0.f; }
  const float* w0p = &Wqkv[(size_t)tid * 128];
  const float* w1p = &Wqkv[(size_t)(tid + 256) * 128];
  const float* w2p = &Wqkv[(size_t)(tid + 512) * 128];
  for (int k4 = 0; k4 < 128; k4 += 4) {
    float4 w0 = *(const float4*)&w0p[k4];
    float4 w1 = *(const float4*)&w1p[k4];
    float4 w2 = *(const float4*)&w2p[k4];
#pragma unroll
    for (int r = 0; r < 8; ++r) {
      float4 xv = *(const float4*)&xl[r][k4];
      acc[r][0] += xv.x * w0.x + xv.y * w0.y + xv.z * w0.z + xv.w * w0.w;
      acc[r][1] += xv.x * w1.x + xv.y * w1.y + xv.z * w1.z + xv.w * w1.w;
      acc[r][2] += xv.x * w2.x + xv.y * w2.y + xv.z * w2.z + xv.w * w2.w;
    }
  }
  const int h = tid >> 5, d = tid & 31;
#pragma unroll
  for (int r = 0; r < 8; ++r) {
    int row = rowbase + r, b = row >> 11, pp = row & 2047;
    size_t base = ((size_t)(b * 8 + h) * 2048 + pp) * 32 + d;
    q_ws[base] = f2bf(acc[r][0] * 0.17677669529663687f);  // 1/sqrt(32)
    k_ws[base] = f2bf(acc[r][1]);
    v_t[((size_t)(b * 8 + h) * 32 + d) * 2048 + pp] = f2bf(acc[r][2]);
  }
}

// ---------------- kernel 2: fused attention ----------------
#define RAW_BARRIER() do { \
  asm volatile("s_waitcnt lgkmcnt(0)" ::: "memory"); \
  __builtin_amdgcn_sched_barrier(0); \
  __builtin_amdgcn_s_barrier(); \
  __builtin_amdgcn_sched_barrier(0); \
} while (0)

#define FULL_BARRIER() do { \
  asm volatile("s_waitcnt vmcnt(0) lgkmcnt(0)" ::: "memory"); \
  __builtin_amdgcn_sched_barrier(0); \
  __builtin_amdgcn_s_barrier(); \
  __builtin_amdgcn_sched_barrier(0); \
} while (0)

// stage K tile (frag-order) and V tile (frag-order, from transposed v_t)
#define STAGE_KV(BUF, KQ) do { \
  _Pragma("unroll") \
  for (int i_ = 0; i_ < 4; ++i_) { \
    int c_ = w * 4 + i_; int hc_ = c_ >> 1; int sc_ = c_ & 1; \
    load_lds_128(&k_ws[((size_t)((b * 8 + hc_) * 2048) + (KQ) + sc_ * 16 + ln) * 32 + lg * 8], \
                 &Kb[BUF][c_ * 512]); \
    load_lds_128(&v_t[((size_t)((b * 8 + hc_) * 32) + sc_ * 16 + ln) * 2048 + (KQ) + lg * 8], \
                 &Vb[BUF][c_ * 512]); \
  } \
} while (0)

#define BIAS_LOAD(BREG, KQ) do { \
  _Pragma("unroll") \
  for (int g_ = 0; g_ < 8; ++g_) \
    BREG[g_] = *(const float4*)&bias[(size_t)g_ * 4194304 + (size_t)prow * 2048 + (KQ) + qs * 4]; \
} while (0)

#define BODY(S, CUR, BC, BN) do { \
  FULL_BARRIER(); /* K/V[CUR] + bias BC ready */ \
  const int kq0_ = kv0 + (S) * 32; \
  if ((S) + 1 < 32) { STAGE_KV(1 - (CUR), kq0_ + 32); } \
  /* ---- S = Q K^T (per-wave: 2 heads) ---- */ \
  _Pragma("unroll") \
  for (int hh = 0; hh < 2; ++hh) { \
    const int h_ = 2 * w + hh; \
    _Pragma("unroll") \
    for (int qt = 0; qt < 2; ++qt) { \
      short8v kf = *(const short8v*)&Kb[CUR][(size_t)(h_ * 2 + qt) * 512 + l * 8]; \
      _Pragma("unroll") \
      for (int pt = 0; pt < 2; ++pt) { \
        f32x4 s4 = __builtin_amdgcn_mfma_f32_16x16x32_bf16( \
            qf[hh][pt], kf, (f32x4){0.f, 0.f, 0.f, 0.f}, 0, 0, 0); \
        _Pragma("unroll") \
        for (int r = 0; r < 4; ++r) \
          Sb[h_ * 1088 + (pt * 16 + lg * 4 + r) * 32 + qt * 16 + ln] = s4[r]; \
      } \
    } \
  } \
  RAW_BARRIER(); /* S ready; prefetches stay in flight */ \
  { /* ---- talking-heads mix + bias + online softmax (thread = (p,qs)) ---- */ \
    float4 sv[8]; \
    _Pragma("unroll") \
    for (int h = 0; h < 8; ++h) sv[h] = *(const float4*)&Sb[h * 1088 + p_mix * 32 + qs * 4]; \
    if ((S) + 1 < 32) { BIAS_LOAD(BN, kq0_ + 32); } \
    _Pragma("unroll") \
    for (int g = 0; g < 8; ++g) { \
      float4 t4 = BC[g]; \
      _Pragma("unroll") \
      for (int h = 0; h < 8; ++h) { \
        const float wgh = wt[g * 8 + h]; \
        t4.x += wgh * sv[h].x; t4.y += wgh * sv[h].y; \
        t4.z += wgh * sv[h].z; t4.w += wgh * sv[h].w; \
      } \
      float mx = fmaxf(fmaxf(t4.x, t4.y), fmaxf(t4.z, t4.w)); \
      mx = fmaxf(mx, __shfl_xor(mx, 1)); \
      mx = fmaxf(mx, __shfl_xor(mx, 2)); \
      mx = fmaxf(mx, __shfl_xor(mx, 4)); \
      const float mnew = fmaxf(mreg[g], mx); \
      const float a_ = __expf(mreg[g] - mnew); \
      mreg[g] = mnew; \
      float ex = __expf(t4.x - mnew), ey = __expf(t4.y - mnew); \
      float ez = __expf(t4.z - mnew), ew = __expf(t4.w - mnew); \
      float ls = ex + ey + ez + ew; \
      ls += __shfl_xor(ls, 1); ls += __shfl_xor(ls, 2); ls += __shfl_xor(ls, 4); \
      lreg[g] = lreg[g] * a_ + ls; \
      if (qs == 0) Sb[g * 1088 + 1024 + p_mix] = a_; /* alpha in S pad */ \
      unsigned u0 = (unsigned)f2bf(ex) | ((unsigned)f2bf(ey) << 16); \
      unsigned u1 = (unsigned)f2bf(ez) | ((unsigned)f2bf(ew) << 16); \
      uint2 pk; pk.x = u0; pk.y = u1; \
      *(uint2*)&Pb[(size_t)((g * 2 + (p_mix >> 4)) * 64 + (qs >> 1) * 16 + (p_mix & 15)) * 8 + (qs & 1) * 4] = pk; \
    } \
  } \
  RAW_BARRIER(); /* P~ + alpha ready */ \
  /* ---- O = diag(alpha) O + P~ V ---- */ \
  _Pragma("unroll") \
  for (int hh = 0; hh < 2; ++hh) { \
    const int h_ = 2 * w + hh; \
    _Pragma("unroll") \
    for (int pt = 0; pt < 2; ++pt) { \
      float4 av = *(const float4*)&Sb[h_ * 1088 + 1024 + pt * 16 + lg * 4]; \
      short8v pa = *(const short8v*)&Pb[(size_t)((h_ * 2 + pt) * 64 + l) * 8]; \
      _Pragma("unroll") \
      for (int dt = 0; dt < 2; ++dt) { \
        f32x4 o = Of[hh][pt][dt]; \
        o[0] *= av.x; o[1] *= av.y; o[2] *= av.z; o[3] *= av.w; \
        short8v vf = *(const short8v*)&Vb[CUR][(size_t)(h_ * 2 + dt) * 512 + l * 8]; \
        Of[hh][pt][dt] = __builtin_amdgcn_mfma_f32_16x16x32_bf16(pa, vf, o, 0, 0, 0); \
      } \
    } \
  } \
} while (0)

__global__ __launch_bounds__(256, 1) void attn_kernel(
    const unsigned short* __restrict__ q_ws, const unsigned short* __restrict__ k_ws,
    const unsigned short* __restrict__ v_t, const float* __restrict__ bias,
    const float* __restrict__ Wtalk, float* __restrict__ pm, float* __restrict__ pl,
    float* __restrict__ pO) {
  __shared__ __align__(16) unsigned short Kb[2][8192];  // K frags, dbuf
  __shared__ __align__(16) unsigned short Vb[2][8192];  // V frags, dbuf
  __shared__ __align__(16) float Sb[8 * 1088];          // S[h][p][32] (+pad: alpha)
  __shared__ __align__(16) unsigned short Pb[8192];     // P~ frags (bf16)

  const int qt_blk = blockIdx.x, split = blockIdx.y, b = blockIdx.z;
  const int q0 = qt_blk * 32, kv0 = split * 1024;
  const int tid = threadIdx.x, w = tid >> 6, l = tid & 63, lg = l >> 4, ln = l & 15;
  const int p_mix = tid >> 3, qs = tid & 7, prow = q0 + p_mix;

  float wt[64];
#pragma unroll
  for (int i = 0; i < 64; ++i) wt[i] = Wtalk[i];

  short8v qf[2][2];
#pragma unroll
  for (int hh = 0; hh < 2; ++hh)
#pragma unroll
    for (int pt = 0; pt < 2; ++pt) {
      int h = 2 * w + hh;
      size_t a = ((size_t)((b * 8 + h) * 2048) + q0 + pt * 16 + ln) * 32 + lg * 8;
      qf[hh][pt] = *(const short8v*)&q_ws[a];
    }

  f32x4 Of[2][2][2];
#pragma unroll
  for (int hh = 0; hh < 2; ++hh)
#pragma unroll
    for (int pt = 0; pt < 2; ++pt)
#pragma unroll
      for (int dt = 0; dt < 2; ++dt) Of[hh][pt][dt] = (f32x4){0.f, 0.f, 0.f, 0.f};

  float mreg[8], lreg[8];
#pragma unroll
  for (int g = 0; g < 8; ++g) { mreg[g] = -1e30f; lreg[g] = 0.f; }

  float4 BA[8], BB[8];
  STAGE_KV(0, kv0);
  BIAS_LOAD(BA, kv0);

  for (int s2 = 0; s2 < 16; ++s2) {
    BODY(2 * s2, 0, BA, BB);
    BODY(2 * s2 + 1, 1, BB, BA);
  }

  // ---- write partials (unnormalized O, m, l) ----
  const size_t ob = (size_t)((split * 2 + b) * 8);
#pragma unroll
  for (int hh = 0; hh < 2; ++hh)
#pragma unroll
    for (int pt = 0; pt < 2; ++pt)
#pragma unroll
      for (int dt = 0; dt < 2; ++dt)
#pragma unroll
        for (int r = 0; r < 4; ++r) {
          int h = 2 * w + hh;
          size_t idx = ((ob + h) * 2048 + q0 + pt * 16 + lg * 4 + r) * 32 + dt * 16 + ln;
          pO[idx] = Of[hh][pt][dt][r];
        }
  if (qs == 0) {
#pragma unroll
    for (int g = 0; g < 8; ++g) {
      size_t idx = (ob + g) * 2048 + prow;
      pm[idx] = mreg[g];
      pl[idx] = lreg[g];
    }
  }
}

// ---------------- kernel 3: combine + projection ----------------
__global__ __launch_bounds__(256) void comb_kernel(
    const float* __restrict__ pm, const float* __restrict__ pl,
    const float* __restrict__ pO, const float* __restrict__ Wproj,
    float* __restrict__ out) {
  __shared__ float ol[8][256];
  const int tid = threadIdx.x;
  const int rowbase = blockIdx.x * 8;
  {
    const int g = tid >> 5, d = tid & 31;
    for (int r = 0; r < 8; ++r) {
      int row = rowbase + r, b = row >> 11, p = row & 2047;
      size_t b0 = ((size_t)(b * 8 + g) * 2048 + p);
      float m0 = pm[b0], m1 = pm[b0 + 32768];
      float l0 = pl[b0], l1 = pl[b0 + 32768];
      float mx = fmaxf(m0, m1);
      float w0 = __expf(m0 - mx), w1 = __expf(m1 - mx);
      float o0 = pO[b0 * 32 + d], o1 = pO[(b0 + 32768) * 32 + d];
      ol[r][tid] = (o0 * w0 + o1 * w1) / (l0 * w0 + l1 * w1);
    }
  }
  __syncthreads();
  const int j = tid & 127, rh = tid >> 7;
  float acc[8];
#pragma unroll
  for (int r = 0; r < 8; ++r) acc[r] = 0.f;
  for (int c4 = 0; c4 < 128; c4 += 4) {
    float4 wv = *(const float4*)&Wproj[(size_t)j * 256 + rh * 128 + c4];
#pragma unroll
    for (int r = 0; r < 8; ++r) {
      float4 ov = *(const float4*)&ol[r][rh * 128 + c4];
      acc[r] += ov.x * wv.x + ov.y * wv.y + ov.z * wv.z + ov.w * wv.w;
    }
  }
  __syncthreads();
  float* red = &ol[0][0];  // reuse as red[8][128][2]
#pragma unroll
  for (int r = 0; r < 8; ++r) red[(r * 128 + j) * 2 + rh] = acc[r];
  __syncthreads();
#pragma unroll
  for (int rr = 0; rr < 4; ++rr) {
    int r = (tid >> 7) * 4 + rr;
    int row = rowbase + r;
    out[(size_t)row * 128 + (tid & 127)] =
        red[(r * 128 + (tid & 127)) * 2] + red[(r * 128 + (tid & 127)) * 2 + 1];
  }
}

extern "C" void kernel_launch(void* const* d_in, const int* in_sizes, int n_in,
                              void* d_out, int out_size, void* d_ws, size_t ws_size,
                              hipStream_t stream) {
  const float* x     = (const float*)d_in[0];
  const float* bias  = (const float*)d_in[1];
  const float* Wqkv  = (const float*)d_in[2];
  const float* Wtalk = (const float*)d_in[3];
  const float* Wproj = (const float*)d_in[4];
  float* out = (float*)d_out;
  char* ws = (char*)d_ws;
  unsigned short* q_ws = (unsigned short*)(ws);
  unsigned short* k_ws = (unsigned short*)(ws + (2u << 20));
  unsigned short* v_t  = (unsigned short*)(ws + (4u << 20));
  float* pm = (float*)(ws + (6u << 20));
  float* pl = (float*)(ws + (6u << 20) + 262144);
  float* pO = (float*)(ws + (7u << 20));

  qkv_kernel<<<512, 256, 0, stream>>>(x, Wqkv, q_ws, k_ws, v_t);
  attn_kernel<<<dim3(64, 2, 2), 256, 0, stream>>>(q_ws, k_ws, v_t, bias, Wtalk, pm, pl, pO);
  comb_kernel<<<512, 256, 0, stream>>>(pm, pl, pO, Wproj, out);
}

// Round 6
// 316.324 us; speedup vs baseline: 1.1396x; 1.1396x over previous
//
#include <hip/hip_runtime.h>

// Talking-heads MHSA, MI355X (gfx950).
// k1: QKV projection (f32 GEMM, outputs bf16; V stored transposed [b][h][d][p])
// k2: fused flash attention, all 8 heads per block. K/V/bias fragments are
//     loaded global->VGPR (L2-resident), software-prefetched one body ahead.
//     LDS holds only S (f32, for the talking-heads all-head gather) and P~.
//     KV-split adaptive (2/4/8) so the grid is 512-1024 blocks -> 2-3
//     independent blocks/CU for latency hiding (round-3 fix: was 1 block/CU,
//     11.3% occupancy, 72% stall).
// k3: split-combine + output projection.

typedef __attribute__((ext_vector_type(8))) short short8v;  // 8 x bf16
typedef __attribute__((ext_vector_type(4))) float f32x4;

static __device__ __forceinline__ unsigned short f2bf(float f) {
  union { float f; unsigned u; } v; v.f = f;
  return (unsigned short)((v.u + 0x7FFFu + ((v.u >> 16) & 1u)) >> 16);
}

#define RAW_BARRIER() do { \
  asm volatile("s_waitcnt lgkmcnt(0)" ::: "memory"); \
  __builtin_amdgcn_sched_barrier(0); \
  __builtin_amdgcn_s_barrier(); \
  __builtin_amdgcn_sched_barrier(0); \
} while (0)

// ---------------- kernel 1: QKV projection ----------------
__global__ __launch_bounds__(256) void qkv_kernel(
    const float* __restrict__ x, const float* __restrict__ Wqkv,
    unsigned short* __restrict__ q_ws, unsigned short* __restrict__ k_ws,
    unsigned short* __restrict__ v_t) {
  __shared__ float xl[8][128];
  const int tid = threadIdx.x;
  const int rowbase = blockIdx.x * 8;
  {
    int r = tid >> 5, k4 = (tid & 31) * 4;
    *(float4*)&xl[r][k4] = *(const float4*)&x[(size_t)(rowbase + r) * 128 + k4];
  }
  __syncthreads();
  float acc[8][3];
#pragma unroll
  for (int r = 0; r < 8; ++r) { acc[r][0] = 0.f; acc[r][1] = 0.f; acc[r][2] = 0.f; }
  const float* w0p = &Wqkv[(size_t)tid * 128];
  const float* w1p = &Wqkv[(size_t)(tid + 256) * 128];
  const float* w2p = &Wqkv[(size_t)(tid + 512) * 128];
  for (int k4 = 0; k4 < 128; k4 += 4) {
    float4 w0 = *(const float4*)&w0p[k4];
    float4 w1 = *(const float4*)&w1p[k4];
    float4 w2 = *(const float4*)&w2p[k4];
#pragma unroll
    for (int r = 0; r < 8; ++r) {
      float4 xv = *(const float4*)&xl[r][k4];
      acc[r][0] += xv.x * w0.x + xv.y * w0.y + xv.z * w0.z + xv.w * w0.w;
      acc[r][1] += xv.x * w1.x + xv.y * w1.y + xv.z * w1.z + xv.w * w1.w;
      acc[r][2] += xv.x * w2.x + xv.y * w2.y + xv.z * w2.z + xv.w * w2.w;
    }
  }
  const int h = tid >> 5, d = tid & 31;
#pragma unroll
  for (int r = 0; r < 8; ++r) {
    int row = rowbase + r, b = row >> 11, pp = row & 2047;
    size_t base = ((size_t)(b * 8 + h) * 2048 + pp) * 32 + d;
    q_ws[base] = f2bf(acc[r][0] * 0.17677669529663687f);  // 1/sqrt(32)
    k_ws[base] = f2bf(acc[r][1]);
    v_t[((size_t)(b * 8 + h) * 32 + d) * 2048 + pp] = f2bf(acc[r][2]);
  }
}

// ---------------- kernel 2: fused attention ----------------
template <int SPLIT>
__global__ __launch_bounds__(256, 2) void attn_kernel(
    const unsigned short* __restrict__ q_ws, const unsigned short* __restrict__ k_ws,
    const unsigned short* __restrict__ v_t, const float* __restrict__ bias,
    const float* __restrict__ Wtalk, float* __restrict__ pm, float* __restrict__ pl,
    float* __restrict__ pO) {
  constexpr int NB = 64 / SPLIT;  // 32-key bodies per block
  __shared__ __align__(16) float Sb[8 * 1088];          // S[h][p][32] + alpha pad
  __shared__ __align__(16) unsigned short Pb[8192];     // P~ frags (bf16)

  const int qt_blk = blockIdx.x, split = blockIdx.y, b = blockIdx.z;
  const int q0 = qt_blk * 32, kv0 = split * (2048 / SPLIT);
  const int tid = threadIdx.x, w = tid >> 6, l = tid & 63, lg = l >> 4, ln = l & 15;
  const int p_mix = tid >> 3, qs = tid & 7, prow = q0 + p_mix;

  float wt[64];  // uniform -> compiler keeps in SGPRs
#pragma unroll
  for (int i = 0; i < 64; ++i) wt[i] = Wtalk[i];

  short8v qf[2][2];
#pragma unroll
  for (int hh = 0; hh < 2; ++hh)
#pragma unroll
    for (int pt = 0; pt < 2; ++pt) {
      int h = 2 * w + hh;
      size_t a = ((size_t)((b * 8 + h) * 2048) + q0 + pt * 16 + ln) * 32 + lg * 8;
      qf[hh][pt] = *(const short8v*)&q_ws[a];
    }

  f32x4 Of[2][2][2];
#pragma unroll
  for (int hh = 0; hh < 2; ++hh)
#pragma unroll
    for (int pt = 0; pt < 2; ++pt)
#pragma unroll
      for (int dt = 0; dt < 2; ++dt) Of[hh][pt][dt] = (f32x4){0.f, 0.f, 0.f, 0.f};

  float mreg[8], lreg[8];
#pragma unroll
  for (int g = 0; g < 8; ++g) { mreg[g] = -1e30f; lreg[g] = 0.f; }

  // per-lane fragment base pointers (identical addressing to the old staging,
  // so the verified k-permutation-invariant sigma is unchanged)
  const unsigned short *kB[2][2], *vB[2][2];
#pragma unroll
  for (int hh = 0; hh < 2; ++hh)
#pragma unroll
    for (int sc = 0; sc < 2; ++sc) {
      kB[hh][sc] = k_ws + ((size_t)(b * 8 + 2 * w + hh) * 2048 + kv0 + sc * 16 + ln) * 32 + lg * 8;
      vB[hh][sc] = v_t + ((size_t)(b * 8 + 2 * w + hh) * 32 + sc * 16 + ln) * 2048 + kv0 + lg * 8;
    }
  const float* bB = bias + (size_t)prow * 2048 + kv0 + qs * 4;  // + g*4194304 + s*32

  // preload body 0 fragments
  short8v kf[2][2], vf[2][2];
  float4 bf[8];
#pragma unroll
  for (int hh = 0; hh < 2; ++hh)
#pragma unroll
    for (int sc = 0; sc < 2; ++sc) {
      kf[hh][sc] = *(const short8v*)kB[hh][sc];
      vf[hh][sc] = *(const short8v*)vB[hh][sc];
    }
#pragma unroll
  for (int g = 0; g < 8; ++g) bf[g] = *(const float4*)(bB + (size_t)g * 4194304);

#pragma unroll 2
  for (int s = 0; s < NB; ++s) {
    const int sn = (s + 1 < NB) ? s + 1 : s;  // last iter reloads self (harmless)

    // ---- S = Q K^T (per-wave: 2 heads) ----
#pragma unroll
    for (int hh = 0; hh < 2; ++hh) {
      const int h_ = 2 * w + hh;
#pragma unroll
      for (int qt = 0; qt < 2; ++qt) {
#pragma unroll
        for (int pt = 0; pt < 2; ++pt) {
          f32x4 s4 = __builtin_amdgcn_mfma_f32_16x16x32_bf16(
              qf[hh][pt], kf[hh][qt], (f32x4){0.f, 0.f, 0.f, 0.f}, 0, 0, 0);
#pragma unroll
          for (int r = 0; r < 4; ++r)
            Sb[h_ * 1088 + (pt * 16 + lg * 4 + r) * 32 + qt * 16 + ln] = s4[r];
        }
      }
    }
    RAW_BARRIER();  // Sb ready (reg prefetches stay in flight)

    // prefetch next K (kf dead after QK^T -> single-buffer rotate)
    short8v kf_n[2][2];
#pragma unroll
    for (int hh = 0; hh < 2; ++hh)
#pragma unroll
      for (int sc = 0; sc < 2; ++sc)
        kf_n[hh][sc] = *(const short8v*)(kB[hh][sc] + (size_t)sn * 1024);

    // ---- talking-heads mix + bias + online softmax (thread = (p,qs)) ----
    {
      float4 sv[8];
#pragma unroll
      for (int h = 0; h < 8; ++h)
        sv[h] = *(const float4*)&Sb[h * 1088 + p_mix * 32 + qs * 4];
#pragma unroll
      for (int g = 0; g < 8; ++g) {
        float4 t4 = bf[g];
#pragma unroll
        for (int h = 0; h < 8; ++h) {
          const float wgh = wt[g * 8 + h];
          t4.x += wgh * sv[h].x; t4.y += wgh * sv[h].y;
          t4.z += wgh * sv[h].z; t4.w += wgh * sv[h].w;
        }
        float mx = fmaxf(fmaxf(t4.x, t4.y), fmaxf(t4.z, t4.w));
        mx = fmaxf(mx, __shfl_xor(mx, 1));
        mx = fmaxf(mx, __shfl_xor(mx, 2));
        mx = fmaxf(mx, __shfl_xor(mx, 4));
        const float mnew = fmaxf(mreg[g], mx);
        const float a_ = __expf(mreg[g] - mnew);
        mreg[g] = mnew;
        float ex = __expf(t4.x - mnew), ey = __expf(t4.y - mnew);
        float ez = __expf(t4.z - mnew), ew = __expf(t4.w - mnew);
        float ls = ex + ey + ez + ew;
        ls += __shfl_xor(ls, 1); ls += __shfl_xor(ls, 2); ls += __shfl_xor(ls, 4);
        lreg[g] = lreg[g] * a_ + ls;
        if (qs == 0) Sb[g * 1088 + 1024 + p_mix] = a_;  // alpha in S pad
        unsigned u0 = (unsigned)f2bf(ex) | ((unsigned)f2bf(ey) << 16);
        unsigned u1 = (unsigned)f2bf(ez) | ((unsigned)f2bf(ew) << 16);
        uint2 pk; pk.x = u0; pk.y = u1;
        *(uint2*)&Pb[(size_t)((g * 2 + (p_mix >> 4)) * 64 + (qs >> 1) * 16 + (p_mix & 15)) * 8 + (qs & 1) * 4] = pk;
      }
    }

    // prefetch next bias (bf consumed above -> single-buffer rotate)
    float4 bf_n[8];
#pragma unroll
    for (int g = 0; g < 8; ++g)
      bf_n[g] = *(const float4*)(bB + (size_t)g * 4194304 + sn * 32);

    RAW_BARRIER();  // P~ + alpha ready

    // ---- O = diag(alpha) O + P~ V ----
#pragma unroll
    for (int hh = 0; hh < 2; ++hh) {
      const int h_ = 2 * w + hh;
#pragma unroll
      for (int pt = 0; pt < 2; ++pt) {
        float4 av = *(const float4*)&Sb[h_ * 1088 + 1024 + pt * 16 + lg * 4];
        short8v pa = *(const short8v*)&Pb[(size_t)((h_ * 2 + pt) * 64 + l) * 8];
#pragma unroll
        for (int dt = 0; dt < 2; ++dt) {
          f32x4 o = Of[hh][pt][dt];
          o[0] *= av.x; o[1] *= av.y; o[2] *= av.z; o[3] *= av.w;
          Of[hh][pt][dt] = __builtin_amdgcn_mfma_f32_16x16x32_bf16(pa, vf[hh][dt], o, 0, 0, 0);
        }
      }
    }

    // prefetch next V (vf consumed in PV above)
    short8v vf_n[2][2];
#pragma unroll
    for (int hh = 0; hh < 2; ++hh)
#pragma unroll
      for (int sc = 0; sc < 2; ++sc)
        vf_n[hh][sc] = *(const short8v*)(vB[hh][sc] + sn * 32);

    // rotate
#pragma unroll
    for (int hh = 0; hh < 2; ++hh)
#pragma unroll
      for (int sc = 0; sc < 2; ++sc) { kf[hh][sc] = kf_n[hh][sc]; vf[hh][sc] = vf_n[hh][sc]; }
#pragma unroll
    for (int g = 0; g < 8; ++g) bf[g] = bf_n[g];
  }

  // ---- write partials (unnormalized O, m, l) ----
  const size_t ob = (size_t)((split * 2 + b) * 8);
#pragma unroll
  for (int hh = 0; hh < 2; ++hh)
#pragma unroll
    for (int pt = 0; pt < 2; ++pt)
#pragma unroll
      for (int dt = 0; dt < 2; ++dt)
#pragma unroll
        for (int r = 0; r < 4; ++r) {
          int h = 2 * w + hh;
          size_t idx = ((ob + h) * 2048 + q0 + pt * 16 + lg * 4 + r) * 32 + dt * 16 + ln;
          pO[idx] = Of[hh][pt][dt][r];
        }
  if (qs == 0) {
#pragma unroll
    for (int g = 0; g < 8; ++g) {
      size_t idx = (ob + g) * 2048 + prow;
      pm[idx] = mreg[g];
      pl[idx] = lreg[g];
    }
  }
}

// ---------------- kernel 3: combine + projection ----------------
template <int SPLIT>
__global__ __launch_bounds__(256) void comb_kernel(
    const float* __restrict__ pm, const float* __restrict__ pl,
    const float* __restrict__ pO, const float* __restrict__ Wproj,
    float* __restrict__ out) {
  __shared__ float ol[8][256];
  const int tid = threadIdx.x;
  const int rowbase = blockIdx.x * 8;
  {
    const int g = tid >> 5, d = tid & 31;
    for (int r = 0; r < 8; ++r) {
      int row = rowbase + r, b = row >> 11, p = row & 2047;
      size_t b0 = ((size_t)(b * 8 + g) * 2048 + p);
      float ms[SPLIT];
      float mx = -1e30f;
#pragma unroll
      for (int s = 0; s < SPLIT; ++s) {
        ms[s] = pm[b0 + (size_t)s * 32768];
        mx = fmaxf(mx, ms[s]);
      }
      float den = 0.f, acc = 0.f;
#pragma unroll
      for (int s = 0; s < SPLIT; ++s) {
        float ww = __expf(ms[s] - mx);
        den += ww * pl[b0 + (size_t)s * 32768];
        acc += ww * pO[(b0 + (size_t)s * 32768) * 32 + d];
      }
      ol[r][tid] = acc / den;
    }
  }
  __syncthreads();
  const int j = tid & 127, rh = tid >> 7;
  float acc[8];
#pragma unroll
  for (int r = 0; r < 8; ++r) acc[r] = 0.f;
  for (int c4 = 0; c4 < 128; c4 += 4) {
    float4 wv = *(const float4*)&Wproj[(size_t)j * 256 + rh * 128 + c4];
#pragma unroll
    for (int r = 0; r < 8; ++r) {
      float4 ov = *(const float4*)&ol[r][rh * 128 + c4];
      acc[r] += ov.x * wv.x + ov.y * wv.y + ov.z * wv.z + ov.w * wv.w;
    }
  }
  __syncthreads();
  float* red = &ol[0][0];  // reuse as red[8][128][2]
#pragma unroll
  for (int r = 0; r < 8; ++r) red[(r * 128 + j) * 2 + rh] = acc[r];
  __syncthreads();
#pragma unroll
  for (int rr = 0; rr < 4; ++rr) {
    int r = (tid >> 7) * 4 + rr;
    int row = rowbase + r;
    out[(size_t)row * 128 + (tid & 127)] =
        red[(r * 128 + (tid & 127)) * 2] + red[(r * 128 + (tid & 127)) * 2 + 1];
  }
}

extern "C" void kernel_launch(void* const* d_in, const int* in_sizes, int n_in,
                              void* d_out, int out_size, void* d_ws, size_t ws_size,
                              hipStream_t stream) {
  const float* x     = (const float*)d_in[0];
  const float* bias  = (const float*)d_in[1];
  const float* Wqkv  = (const float*)d_in[2];
  const float* Wtalk = (const float*)d_in[3];
  const float* Wproj = (const float*)d_in[4];
  float* out = (float*)d_out;
  char* ws = (char*)d_ws;
  unsigned short* q_ws = (unsigned short*)(ws);
  unsigned short* k_ws = (unsigned short*)(ws + (2u << 20));
  unsigned short* v_t  = (unsigned short*)(ws + (4u << 20));

  const size_t base = 6291456;           // q/k/v end
  const size_t per_split = 4456448;      // pm(128K) + pl(128K) + pO(4M) per split
  int SPLIT = (ws_size >= base + 8 * per_split) ? 8
            : (ws_size >= base + 4 * per_split) ? 4 : 2;
  float* pm = (float*)(ws + base);
  float* pl = (float*)(ws + base + (size_t)SPLIT * 131072);
  float* pO = (float*)(ws + base + (size_t)SPLIT * 262144);

  qkv_kernel<<<512, 256, 0, stream>>>(x, Wqkv, q_ws, k_ws, v_t);
  if (SPLIT == 8) {
    attn_kernel<8><<<dim3(64, 8, 2), 256, 0, stream>>>(q_ws, k_ws, v_t, bias, Wtalk, pm, pl, pO);
    comb_kernel<8><<<512, 256, 0, stream>>>(pm, pl, pO, Wproj, out);
  } else if (SPLIT == 4) {
    attn_kernel<4><<<dim3(64, 4, 2), 256, 0, stream>>>(q_ws, k_ws, v_t, bias, Wtalk, pm, pl, pO);
    comb_kernel<4><<<512, 256, 0, stream>>>(pm, pl, pO, Wproj, out);
  } else {
    attn_kernel<2><<<dim3(64, 2, 2), 256, 0, stream>>>(q_ws, k_ws, v_t, bias, Wtalk, pm, pl, pO);
    comb_kernel<2><<<512, 256, 0, stream>>>(pm, pl, pO, Wproj, out);
  }
}